// Round 1
// baseline (21.704 us; speedup 1.0000x reference)
//
#include <hip/hip_runtime.h>

#define N_CLASSES 512
#define EPS_F 1e-7f

// K1: per-sample NLL, per-block LDS class-histogram, atomic flush of
// non-empty classes to global partial sums/counts.
__global__ __launch_bounds__(1024) void nll_hist_kernel(
    const float* __restrict__ close_er,
    const int*   __restrict__ y,
    const float* __restrict__ max_dis,
    const float* __restrict__ margin_p,
    float* __restrict__ g_sums,
    float* __restrict__ g_counts,
    int n)
{
    __shared__ float        s_md[N_CLASSES];
    __shared__ float        s_sum[N_CLASSES];
    __shared__ unsigned int s_cnt[N_CLASSES];

    const int tid = threadIdx.x;
    const float margin = margin_p[0];

    for (int c = tid; c < N_CLASSES; c += blockDim.x) {
        s_md[c]  = max_dis[c];
        s_sum[c] = 0.0f;
        s_cnt[c] = 0u;
    }
    __syncthreads();

    for (long long i = (long long)blockIdx.x * blockDim.x + tid; i < n;
         i += (long long)gridDim.x * blockDim.x) {
        const int c = y[i];
        const float ce = close_er[i * (long long)N_CLASSES + c];
        const float x  = ce - s_md[c] - margin;
        // sigmoid, then clamp to [EPS, 1-EPS], then -log — exactly the reference.
        float s = 1.0f / (1.0f + __expf(-x));
        s = fminf(fmaxf(s, EPS_F), 1.0f - EPS_F);
        const float nll = -__logf(s);
        atomicAdd(&s_sum[c], nll);
        atomicAdd(&s_cnt[c], 1u);
    }
    __syncthreads();

    for (int c = tid; c < N_CLASSES; c += blockDim.x) {
        const unsigned int cnt = s_cnt[c];
        if (cnt != 0u) {
            atomicAdd(&g_sums[c],   s_sum[c]);
            atomicAdd(&g_counts[c], (float)cnt);  // exact: counts < 2^24
        }
    }
}

// K2: per-class mean, mean over non-empty classes, single scalar out.
__global__ __launch_bounds__(512) void finalize_kernel(
    const float* __restrict__ g_sums,
    const float* __restrict__ g_counts,
    float* __restrict__ out)
{
    __shared__ float s_m[N_CLASSES];
    __shared__ float s_j[N_CLASSES];

    const int t = threadIdx.x;
    const float cnt  = g_counts[t];
    const bool  ne   = cnt > 0.0f;
    s_m[t] = ne ? (g_sums[t] / cnt) : 0.0f;
    s_j[t] = ne ? 1.0f : 0.0f;
    __syncthreads();

    for (int off = 256; off >= 64; off >>= 1) {
        if (t < off) {
            s_m[t] += s_m[t + off];
            s_j[t] += s_j[t + off];
        }
        __syncthreads();
    }
    if (t < 64) {
        float m = s_m[t];
        float j = s_j[t];
        for (int off = 32; off > 0; off >>= 1) {
            m += __shfl_down(m, off);
            j += __shfl_down(j, off);
        }
        if (t == 0) out[0] = m / j;
    }
}

extern "C" void kernel_launch(void* const* d_in, const int* in_sizes, int n_in,
                              void* d_out, int out_size, void* d_ws, size_t ws_size,
                              hipStream_t stream) {
    const float* close_er = (const float*)d_in[0];
    const int*   y        = (const int*)d_in[1];
    const float* max_dis  = (const float*)d_in[2];
    const float* margin   = (const float*)d_in[3];
    float* out = (float*)d_out;

    const int n = in_sizes[1];  // N samples (y's length)

    float* g_sums   = (float*)d_ws;
    float* g_counts = g_sums + N_CLASSES;

    // Workspace is poisoned (0xAA) before timing and never re-poisoned:
    // zero our 4 KB of accumulators every call.
    hipMemsetAsync(d_ws, 0, 2 * N_CLASSES * sizeof(float), stream);

    const int block = 1024;
    const int grid  = (n + block - 1) / block;  // 256 blocks at N=262144
    nll_hist_kernel<<<grid, block, 0, stream>>>(close_er, y, max_dis, margin,
                                                g_sums, g_counts, n);
    finalize_kernel<<<1, N_CLASSES, 0, stream>>>(g_sums, g_counts, out);
}